// Round 6
// baseline (289.295 us; speedup 1.0000x reference)
//
#include <hip/hip_runtime.h>
#include <math.h>

// Problem constants (fixed by the reference): N=8, B=4096, D=1024.
#define NN 8
#define BB 4096
#define DD 1024
#define CHUNK 256              // elements per block = 64 lanes x 4 floats
#define LOG_2PI 1.8378770664093453f

// R6: per-wave self-paced pipeline, no block-wide drain.
//  - 1 wave per block (64 thr), 4 rows-chunks per row b (grid = 4*BB).
//  - wave issues 16 global_load_lds DMAs back-to-back (16 KB LDS),
//    then consumes step n after s_waitcnt vmcnt(14-2n): compute overlaps
//    its own remaining DMAs and the ~9 other resident waves' DMAs.
//  - wave reads only LDS it wrote itself -> NO __syncthreads anywhere.
//  - log_z combined across the 4 chunk-blocks via one atomicAdd each;
//    out_logz zeroed by hipMemsetAsync on the stream.

#define GLOAD_LDS16(g, l)                                                  \
    __builtin_amdgcn_global_load_lds(                                      \
        (const __attribute__((address_space(1))) unsigned int*)(g),        \
        (__attribute__((address_space(3))) unsigned int*)(l), 16, 0, 0)

#define WAITVM(imm) asm volatile("s_waitcnt vmcnt(" #imm ")" ::: "memory")

__global__ __launch_bounds__(64) void mpc_kernel(
    const float* __restrict__ means,
    const float* __restrict__ logsig,
    float* __restrict__ out_mean,
    float* __restrict__ out_logvar,
    float* __restrict__ out_logz)
{
    __shared__ float smem[16 * CHUNK];   // 16 KB: [2n]=means_n, [2n+1]=logsig_n

    const int blk  = blockIdx.x;
    const int b    = blk >> 2;           // row
    const int c    = blk & 3;            // chunk within row
    const int lane = threadIdx.x;        // 0..63
    const size_t base  = (size_t)b * DD + (size_t)c * CHUNK + (size_t)lane * 4;
    const size_t plane = (size_t)BB * DD;

    // ---- issue all 16 DMAs back-to-back (nothing can sink them) ----
#pragma unroll
    for (int n = 0; n < NN; ++n) {
        GLOAD_LDS16(means  + (size_t)n * plane + base, &smem[(2 * n + 0) * CHUNK]);
        GLOAD_LDS16(logsig + (size_t)n * plane + base, &smem[(2 * n + 1) * CHUNK]);
    }

    // ---- init carry from step 0 (only first 2 DMAs needed) ----
    float m1[4], v1[4], iv1[4];
    float z = 0.0f;
    WAITVM(14);
    {
        float4 mm = *(const float4*)&smem[0 * CHUNK + lane * 4];
        float4 ll = *(const float4*)&smem[1 * CHUNK + lane * 4];
        float m[4] = {mm.x, mm.y, mm.z, mm.w};
        float l[4] = {ll.x, ll.y, ll.z, ll.w};
        for (int j = 0; j < 4; ++j) {
            m1[j]  = m[j];
            v1[j]  = __expf(l[j]);
            iv1[j] = __expf(-l[j]);
        }
    }

#define STEP(n, imm) do {                                                   \
        WAITVM(imm);                                                        \
        float4 mm = *(const float4*)&smem[(2 * (n) + 0) * CHUNK + lane * 4];\
        float4 ll = *(const float4*)&smem[(2 * (n) + 1) * CHUNK + lane * 4];\
        float m2[4] = {mm.x, mm.y, mm.z, mm.w};                             \
        float l2[4] = {ll.x, ll.y, ll.z, ll.w};                             \
        for (int j = 0; j < 4; ++j) {                                       \
            float v2  = __expf(l2[j]);                                      \
            float iv2 = __expf(-l2[j]);                                     \
            float s   = v1[j] + v2 + 1e-6f;                                 \
            float diff = m1[j] - m2[j];                                     \
            z += diff * diff * __builtin_amdgcn_rcpf(s) + __logf(s);        \
            float iv_new = iv1[j] + iv2;                                    \
            float cvar   = __builtin_amdgcn_rcpf(iv_new);                   \
            m1[j]  = cvar * (m1[j] * iv1[j] + m2[j] * iv2);                 \
            v1[j]  = cvar;                                                  \
            iv1[j] = iv_new;                                                \
        }                                                                   \
    } while (0)

    STEP(1, 12);
    STEP(2, 10);
    STEP(3, 8);
    STEP(4, 6);
    STEP(5, 4);
    STEP(6, 2);
    STEP(7, 0);
#undef STEP

    // ---- elementwise outputs ----
    float4 om = make_float4(m1[0], m1[1], m1[2], m1[3]);
    float4 ol = make_float4(__logf(v1[0]), __logf(v1[1]),
                            __logf(v1[2]), __logf(v1[3]));
    *(float4*)(out_mean + base)   = om;
    *(float4*)(out_logvar + base) = ol;

    // ---- wave reduction of z, one atomic per block ----
#pragma unroll
    for (int o = 32; o > 0; o >>= 1)
        z += __shfl_down(z, o, 64);
    if (lane == 0) {
        // per-block share of the constant term: (7*D*LOG_2PI)/4 chunks
        float partial = -0.5f * z - 0.125f * (float)((NN - 1) * DD) * LOG_2PI;
        atomicAdd(out_logz + b, partial);
    }
}

extern "C" void kernel_launch(void* const* d_in, const int* in_sizes, int n_in,
                              void* d_out, int out_size, void* d_ws, size_t ws_size,
                              hipStream_t stream) {
    const float* means  = (const float*)d_in[0];
    const float* logsig = (const float*)d_in[1];
    float* out = (float*)d_out;
    float* out_mean   = out;
    float* out_logvar = out + (size_t)BB * DD;
    float* out_logz   = out + 2 * (size_t)BB * DD;
    hipMemsetAsync(out_logz, 0, BB * sizeof(float), stream);
    mpc_kernel<<<BB * 4, 64, 0, stream>>>(means, logsig, out_mean, out_logvar, out_logz);
}